// Round 4
// baseline (1617.061 us; speedup 1.0000x reference)
//
#include <hip/hip_runtime.h>

#define NA_N 50000
#define NB_N 50000
#define DIM  64
#define NE   30000
#define FE_N 16
#define NBLK_E 469          // ceil(30000/64)
#define NBLK_N 782          // ceil(50000/64)

// ---------------------------------------------------------------------------
// Fused node init: blocks [0,NBLK_N) -> type a, [NBLK_N,2*NBLK_N) -> type b.
// out[n,:] = emb[idx[n],:] @ W + bias
// ---------------------------------------------------------------------------
__global__ __launch_bounds__(256) void k_node_init(
    const int* __restrict__ idx_a, const float* __restrict__ emb_a,
    const float* __restrict__ Wa, const float* __restrict__ ba_, float* __restrict__ out_a,
    const int* __restrict__ idx_b, const float* __restrict__ emb_b,
    const float* __restrict__ Wb, const float* __restrict__ bb_, float* __restrict__ out_b)
{
    __shared__ __align__(16) float XsT[64][68];
    __shared__ __align__(16) float Ws[64][64];

    const bool isA = blockIdx.x < NBLK_N;
    const int  blk = isA ? blockIdx.x : blockIdx.x - NBLK_N;
    const int*   idx  = isA ? idx_a : idx_b;
    const float* emb  = isA ? emb_a : emb_b;
    const float* W    = isA ? Wa : Wb;
    const float* bias = isA ? ba_ : bb_;
    float*       out  = isA ? out_a : out_b;
    const int    N    = isA ? NA_N : NB_N;

    const int t  = threadIdx.x;
    const int n0 = blk * 64;

    {
        const float4* Wv  = (const float4*)W;
        float4*       Wsv = (float4*)&Ws[0][0];
#pragma unroll
        for (int i = 0; i < 4; ++i) Wsv[t + 256 * i] = Wv[t + 256 * i];
    }
    {
        const int r = t >> 2, q = t & 3;
        const int n = n0 + r;
        if (n < N) {
            const int g = idx[n];
            const float4* src = (const float4*)(emb + (size_t)g * DIM);
#pragma unroll
            for (int i = 0; i < 4; ++i) {
                float4 v = src[q * 4 + i];
                XsT[q * 16 + i * 4 + 0][r] = v.x;
                XsT[q * 16 + i * 4 + 1][r] = v.y;
                XsT[q * 16 + i * 4 + 2][r] = v.z;
                XsT[q * 16 + i * 4 + 3][r] = v.w;
            }
        } else {
#pragma unroll
            for (int i = 0; i < 16; ++i) XsT[q * 16 + i][r] = 0.f;
        }
    }
    __syncthreads();

    const int tr = t >> 4, tc = t & 15;
    float acc[4][4] = {};
    for (int d = 0; d < 64; ++d) {
        const float4 xv = *(const float4*)&XsT[d][tr * 4];
        const float4 wv = *(const float4*)&Ws[d][tc * 4];
        acc[0][0] += xv.x * wv.x; acc[0][1] += xv.x * wv.y;
        acc[0][2] += xv.x * wv.z; acc[0][3] += xv.x * wv.w;
        acc[1][0] += xv.y * wv.x; acc[1][1] += xv.y * wv.y;
        acc[1][2] += xv.y * wv.z; acc[1][3] += xv.y * wv.w;
        acc[2][0] += xv.z * wv.x; acc[2][1] += xv.z * wv.y;
        acc[2][2] += xv.z * wv.z; acc[2][3] += xv.z * wv.w;
        acc[3][0] += xv.w * wv.x; acc[3][1] += xv.w * wv.y;
        acc[3][2] += xv.w * wv.z; acc[3][3] += xv.w * wv.w;
    }
    const float4 bv = *(const float4*)(bias + tc * 4);
#pragma unroll
    for (int i = 0; i < 4; ++i) {
        const int n = n0 + tr * 4 + i;
        if (n < N) {
            float4 o;
            o.x = acc[i][0] + bv.x;
            o.y = acc[i][1] + bv.y;
            o.z = acc[i][2] + bv.z;
            o.w = acc[i][3] + bv.w;
            *(float4*)(out + (size_t)n * DIM + tc * 4) = o;
        }
    }
}

// ---------------------------------------------------------------------------
// Fused node update: a-side then b-side by blockIdx.
// out = relu( ssum/max(cnt,1) + x @ root + bias ); optionally re-zero ssum rows
// (owned exclusively by this block) for the next layer.
// ---------------------------------------------------------------------------
__global__ __launch_bounds__(256) void k_node_update(
    const float* __restrict__ xa, const float* __restrict__ roota,
    const float* __restrict__ biasa, float* __restrict__ ssa,
    const float* __restrict__ cnta, float* __restrict__ outa,
    const float* __restrict__ xb, const float* __restrict__ rootb,
    const float* __restrict__ biasb, float* __restrict__ ssb,
    const float* __restrict__ cntb, float* __restrict__ outb,
    int zero_ssum)
{
    __shared__ __align__(16) float XsT[64][68];
    __shared__ __align__(16) float Ws[64][64];

    const bool isA = blockIdx.x < NBLK_N;
    const int  blk = isA ? blockIdx.x : blockIdx.x - NBLK_N;
    const float* x    = isA ? xa : xb;
    const float* root = isA ? roota : rootb;
    const float* bias = isA ? biasa : biasb;
    float*       ssum = isA ? ssa : ssb;
    const float* cnt  = isA ? cnta : cntb;
    float*       out  = isA ? outa : outb;
    const int    N    = isA ? NA_N : NB_N;

    const int t  = threadIdx.x;
    const int n0 = blk * 64;

    {
        const float4* Wv  = (const float4*)root;
        float4*       Wsv = (float4*)&Ws[0][0];
#pragma unroll
        for (int i = 0; i < 4; ++i) Wsv[t + 256 * i] = Wv[t + 256 * i];
    }
    {
        const int r = t >> 2, q = t & 3;
        const int n = n0 + r;
        if (n < N) {
            const float4* src = (const float4*)(x + (size_t)n * DIM);
#pragma unroll
            for (int i = 0; i < 4; ++i) {
                float4 v = src[q * 4 + i];
                XsT[q * 16 + i * 4 + 0][r] = v.x;
                XsT[q * 16 + i * 4 + 1][r] = v.y;
                XsT[q * 16 + i * 4 + 2][r] = v.z;
                XsT[q * 16 + i * 4 + 3][r] = v.w;
            }
        } else {
#pragma unroll
            for (int i = 0; i < 16; ++i) XsT[q * 16 + i][r] = 0.f;
        }
    }
    __syncthreads();

    const int tr = t >> 4, tc = t & 15;
    float acc[4][4] = {};
    for (int d = 0; d < 64; ++d) {
        const float4 xv = *(const float4*)&XsT[d][tr * 4];
        const float4 wv = *(const float4*)&Ws[d][tc * 4];
        acc[0][0] += xv.x * wv.x; acc[0][1] += xv.x * wv.y;
        acc[0][2] += xv.x * wv.z; acc[0][3] += xv.x * wv.w;
        acc[1][0] += xv.y * wv.x; acc[1][1] += xv.y * wv.y;
        acc[1][2] += xv.y * wv.z; acc[1][3] += xv.y * wv.w;
        acc[2][0] += xv.z * wv.x; acc[2][1] += xv.z * wv.y;
        acc[2][2] += xv.z * wv.z; acc[2][3] += xv.z * wv.w;
        acc[3][0] += xv.w * wv.x; acc[3][1] += xv.w * wv.y;
        acc[3][2] += xv.w * wv.z; acc[3][3] += xv.w * wv.w;
    }
    const float4 bv = *(const float4*)(bias + tc * 4);
#pragma unroll
    for (int i = 0; i < 4; ++i) {
        const int n = n0 + tr * 4 + i;
        if (n < N) {
            const float inv = 1.0f / fmaxf(cnt[n], 1.0f);
            float* sp = ssum + (size_t)n * DIM + tc * 4;
            const float4 s = *(const float4*)sp;
            float4 o;
            o.x = fmaxf(acc[i][0] + s.x * inv + bv.x, 0.f);
            o.y = fmaxf(acc[i][1] + s.y * inv + bv.y, 0.f);
            o.z = fmaxf(acc[i][2] + s.z * inv + bv.z, 0.f);
            o.w = fmaxf(acc[i][3] + s.w * inv + bv.w, 0.f);
            *(float4*)(out + (size_t)n * DIM + tc * 4) = o;
            if (zero_ssum) *(float4*)sp = make_float4(0.f, 0.f, 0.f, 0.f);
        }
    }
}

// ---------------------------------------------------------------------------
// Fused edge MLP: h[e,:] = relu( ea[e,:] @ W1 + b1 ), both edge types.
// ---------------------------------------------------------------------------
__global__ __launch_bounds__(256) void k_edge_h(
    const float* __restrict__ ea_ab, const float* __restrict__ W1_ab,
    const float* __restrict__ b1_ab, float* __restrict__ h_ab,
    const float* __restrict__ ea_ba, const float* __restrict__ W1_ba,
    const float* __restrict__ b1_ba, float* __restrict__ h_ba)
{
    __shared__ __align__(16) float As[64][17];
    __shared__ __align__(16) float Ws[16][64];

    const bool isAB = blockIdx.x < NBLK_E;
    const int  blk  = isAB ? blockIdx.x : blockIdx.x - NBLK_E;
    const float* ea = isAB ? ea_ab : ea_ba;
    const float* W1 = isAB ? W1_ab : W1_ba;
    const float* b1 = isAB ? b1_ab : b1_ba;
    float*       h  = isAB ? h_ab : h_ba;

    const int t  = threadIdx.x;
    const int e0 = blk * 64;

    ((float4*)&Ws[0][0])[t] = ((const float4*)W1)[t];
    {
        const int r = t >> 2, q = t & 3;
        const int e = e0 + r;
        float4 v = make_float4(0.f, 0.f, 0.f, 0.f);
        if (e < NE) v = ((const float4*)(ea + (size_t)e * FE_N))[q];
        As[r][q * 4 + 0] = v.x;
        As[r][q * 4 + 1] = v.y;
        As[r][q * 4 + 2] = v.z;
        As[r][q * 4 + 3] = v.w;
    }
    __syncthreads();

    const int tr = t >> 4, tc = t & 15;
    float acc[4][4] = {};
    for (int d = 0; d < 16; ++d) {
        float xv[4];
#pragma unroll
        for (int i = 0; i < 4; ++i) xv[i] = As[tr * 4 + i][d];
        const float4 wv = *(const float4*)&Ws[d][tc * 4];
#pragma unroll
        for (int i = 0; i < 4; ++i) {
            acc[i][0] += xv[i] * wv.x;
            acc[i][1] += xv[i] * wv.y;
            acc[i][2] += xv[i] * wv.z;
            acc[i][3] += xv[i] * wv.w;
        }
    }
    const float4 bv = *(const float4*)(b1 + tc * 4);
#pragma unroll
    for (int i = 0; i < 4; ++i) {
        const int e = e0 + tr * 4 + i;
        if (e < NE) {
            float4 o;
            o.x = fmaxf(acc[i][0] + bv.x, 0.f);
            o.y = fmaxf(acc[i][1] + bv.y, 0.f);
            o.z = fmaxf(acc[i][2] + bv.z, 0.f);
            o.w = fmaxf(acc[i][3] + bv.w, 0.f);
            *(float4*)(h + (size_t)e * DIM + tc * 4) = o;
        }
    }
}

// ---------------------------------------------------------------------------
// Fused degree counts for both edge types.
// ---------------------------------------------------------------------------
__global__ void k_count(const int* __restrict__ dst_ab, const int* __restrict__ dst_ba,
                        float* __restrict__ cnt_b, float* __restrict__ cnt_a)
{
    const int i = blockIdx.x * blockDim.x + threadIdx.x;
    if (i < NE)            atomicAdd(&cnt_b[dst_ab[i]], 1.0f);
    else if (i < 2 * NE)   atomicAdd(&cnt_a[dst_ba[i - NE]], 1.0f);
}

// ---------------------------------------------------------------------------
// Fused message+scatter for both edge types (blockIdx selects type).
//   acc[e,o] = sum_{k<64} h[e,k]*sum_d x[src,d]*W2[k][d*64+o]
//            + sum_d x[src,d]*b2[d*64+o]
// k-slots: 0..63 = W2 rows (h from edge MLP), 64 = b2 (h=1), 65 = pad (h=0).
// Two k-slots per staged pair; h folded into x (hx) so acc accumulates direct.
// ---------------------------------------------------------------------------
__global__ __launch_bounds__(256) void k_msg(
    const float* __restrict__ h_ab, const float* __restrict__ x_ab,
    const int* __restrict__ ei_ab, const float* __restrict__ W2_ab,
    const float* __restrict__ b2_ab, float* __restrict__ ssum_b,
    const float* __restrict__ h_ba, const float* __restrict__ x_ba,
    const int* __restrict__ ei_ba, const float* __restrict__ W2_ba,
    const float* __restrict__ b2_ba, float* __restrict__ ssum_a)
{
    __shared__ __align__(16) float HsT[66][68];    // [k][edge], float4 reads per k
    __shared__ __align__(16) float XsT[64][68];    // [d][edge], float4 reads
    __shared__ __align__(16) float Bs[2][64][64];  // two k-slots: [slot][d][o]

    const bool isAB = blockIdx.x < NBLK_E;
    const int  blk  = isAB ? blockIdx.x : blockIdx.x - NBLK_E;
    const float* h    = isAB ? h_ab : h_ba;
    const float* x    = isAB ? x_ab : x_ba;
    const int*   srcI = isAB ? ei_ab : ei_ba;
    const int*   dstI = srcI + NE;
    const float* W2   = isAB ? W2_ab : W2_ba;
    const float* b2   = isAB ? b2_ab : b2_ba;
    float*       ssum = isAB ? ssum_b : ssum_a;

    const int t  = threadIdx.x;
    const int e0 = blk * 64;

    {   // stage h^T and gathered x^T
        const int r = t >> 2, q = t & 3;
        const int e = e0 + r;
        if (e < NE) {
            const float4* hv = (const float4*)(h + (size_t)e * DIM);
            const int     s  = srcI[e];
            const float4* xv = (const float4*)(x + (size_t)s * DIM);
#pragma unroll
            for (int i = 0; i < 4; ++i) {
                float4 a = hv[q * 4 + i];
                HsT[q * 16 + i * 4 + 0][r] = a.x;
                HsT[q * 16 + i * 4 + 1][r] = a.y;
                HsT[q * 16 + i * 4 + 2][r] = a.z;
                HsT[q * 16 + i * 4 + 3][r] = a.w;
                float4 b = xv[q * 4 + i];
                XsT[q * 16 + i * 4 + 0][r] = b.x;
                XsT[q * 16 + i * 4 + 1][r] = b.y;
                XsT[q * 16 + i * 4 + 2][r] = b.z;
                XsT[q * 16 + i * 4 + 3][r] = b.w;
            }
        } else {
#pragma unroll
            for (int i = 0; i < 16; ++i) {
                HsT[q * 16 + i][r] = 0.f;
                XsT[q * 16 + i][r] = 0.f;
            }
        }
        if (t < 64)       HsT[64][t] = 1.0f;       // b2 slot
        else if (t < 128) HsT[65][t - 64] = 0.0f;  // pad slot
    }

    // register-prefetch B pair 0 (k = 0,1)
    float4 breg[8];
#pragma unroll
    for (int i = 0; i < 8; ++i) {
        const int si   = t + 256 * i;      // float4 slot 0..2047
        const int krow = si >> 10;         // 0 or 1
        const int loc  = si & 1023;
        breg[i] = ((const float4*)(W2 + (size_t)krow * 4096))[loc];
    }

    const int tr = t >> 4, tc = t & 15;
    float acc[4][4] = {};

    for (int p = 0; p < 33; ++p) {
        __syncthreads();                   // staging done (p=0) / Bs consumed (p>0)
        {
            float4* Bv = (float4*)&Bs[0][0][0];
#pragma unroll
            for (int i = 0; i < 8; ++i) Bv[t + 256 * i] = breg[i];
        }
        __syncthreads();

        if (p < 32) {                      // prefetch next pair under compute
            const int k0n = 2 * (p + 1);
#pragma unroll
            for (int i = 0; i < 8; ++i) {
                const int si   = t + 256 * i;
                const int krow = k0n + (si >> 10);
                const int loc  = si & 1023;
                const float* sp = (krow < 64) ? (W2 + (size_t)krow * 4096) : b2;
                breg[i] = ((const float4*)sp)[loc];
            }
        }

        const int k0 = 2 * p;
        const float4 h0 = *(const float4*)&HsT[k0][tr * 4];
        const float4 h1 = *(const float4*)&HsT[k0 + 1][tr * 4];
        const float h0a[4] = { h0.x, h0.y, h0.z, h0.w };
        const float h1a[4] = { h1.x, h1.y, h1.z, h1.w };

#pragma unroll 4
        for (int d = 0; d < 64; ++d) {
            const float4 xv = *(const float4*)&XsT[d][tr * 4];
            const float4 w0 = *(const float4*)&Bs[0][d][tc * 4];
            const float4 w1 = *(const float4*)&Bs[1][d][tc * 4];
            const float xa[4]  = { xv.x, xv.y, xv.z, xv.w };
            const float w0a[4] = { w0.x, w0.y, w0.z, w0.w };
            const float w1a[4] = { w1.x, w1.y, w1.z, w1.w };
            float hx0[4], hx1[4];
#pragma unroll
            for (int i = 0; i < 4; ++i) { hx0[i] = h0a[i] * xa[i]; hx1[i] = h1a[i] * xa[i]; }
#pragma unroll
            for (int i = 0; i < 4; ++i)
#pragma unroll
                for (int j = 0; j < 4; ++j)
                    acc[i][j] += hx0[i] * w0a[j] + hx1[i] * w1a[j];
        }
    }

#pragma unroll
    for (int i = 0; i < 4; ++i) {
        const int e = e0 + tr * 4 + i;
        if (e < NE) {
            const int dn = dstI[e];
            float* p = ssum + (size_t)dn * DIM + tc * 4;
            atomicAdd(p + 0, acc[i][0]);
            atomicAdd(p + 1, acc[i][1]);
            atomicAdd(p + 2, acc[i][2]);
            atomicAdd(p + 3, acc[i][3]);
        }
    }
}

// ---------------------------------------------------------------------------
extern "C" void kernel_launch(void* const* d_in, const int* in_sizes, int n_in,
                              void* d_out, int out_size, void* d_ws, size_t ws_size,
                              hipStream_t stream)
{
    (void)in_sizes; (void)n_in; (void)out_size; (void)ws_size;

    const int*   x_a      = (const int*)d_in[0];
    const int*   x_b      = (const int*)d_in[1];
    const int*   ei_ab    = (const int*)d_in[2];   // [2][E]: row0 src(a), row1 dst(b)
    const int*   ei_ba    = (const int*)d_in[3];   // row0 src(b), row1 dst(a)
    const float* ea_ab    = (const float*)d_in[4];
    const float* ea_ba    = (const float*)d_in[5];
    const float* emb_a    = (const float*)d_in[6];
    const float* emb_b    = (const float*)d_in[7];
    const float* Wn_a     = (const float*)d_in[8];
    const float* bn_a     = (const float*)d_in[9];
    const float* Wn_b     = (const float*)d_in[10];
    const float* bn_b     = (const float*)d_in[11];
    const float* W1_ab    = (const float*)d_in[12];
    const float* b1_ab    = (const float*)d_in[13];
    const float* W2_ab    = (const float*)d_in[14];
    const float* b2_ab    = (const float*)d_in[15];
    const float* W1_ba    = (const float*)d_in[16];
    const float* b1_ba    = (const float*)d_in[17];
    const float* W2_ba    = (const float*)d_in[18];
    const float* b2_ba    = (const float*)d_in[19];
    const float* root0_ab = (const float*)d_in[20];
    const float* bias0_ab = (const float*)d_in[21];
    const float* root0_ba = (const float*)d_in[22];
    const float* bias0_ba = (const float*)d_in[23];
    const float* root1_ab = (const float*)d_in[24];
    const float* bias1_ab = (const float*)d_in[25];
    const float* root1_ba = (const float*)d_in[26];
    const float* bias1_ba = (const float*)d_in[27];

    float* out_a = (float*)d_out;                       // [NA][64]
    float* out_b = (float*)d_out + (size_t)NA_N * DIM;  // [NB][64]

    // workspace layout (floats)
    float* ws     = (float*)d_ws;
    float* ha0    = ws;                           // NA*64
    float* hb0    = ha0   + (size_t)NA_N * DIM;   // NB*64
    float* na1    = hb0   + (size_t)NB_N * DIM;   // NA*64
    float* nb1    = na1   + (size_t)NA_N * DIM;   // NB*64
    float* h_ab   = nb1   + (size_t)NB_N * DIM;   // E*64
    float* h_ba   = h_ab  + (size_t)NE * DIM;     // E*64
    float* cnt_a  = h_ba  + (size_t)NE * DIM;     // NA      } one contiguous
    float* cnt_b  = cnt_a + NA_N;                 // NB      } memset region
    float* ssum_a = cnt_b + NB_N;                 // NA*64   }
    float* ssum_b = ssum_a + (size_t)NA_N * DIM;  // NB*64   }

    const size_t zeroBytes =
        ((size_t)(NA_N + NB_N) + (size_t)(NA_N + NB_N) * DIM) * sizeof(float);

    // zero counts + both ssum buffers (ws is re-poisoned 0xAA before every call)
    hipMemsetAsync(cnt_a, 0, zeroBytes, stream);

    // degree counts (layer-invariant)
    k_count<<<(2 * NE + 255) / 256, 256, 0, stream>>>(ei_ab + NE, ei_ba + NE,
                                                      cnt_b, cnt_a);
    // node init (both types)
    k_node_init<<<2 * NBLK_N, 256, 0, stream>>>(x_a, emb_a, Wn_a, bn_a, ha0,
                                                x_b, emb_b, Wn_b, bn_b, hb0);
    // edge MLP h (layer-invariant, both types)
    k_edge_h<<<2 * NBLK_E, 256, 0, stream>>>(ea_ab, W1_ab, b1_ab, h_ab,
                                             ea_ba, W1_ba, b1_ba, h_ba);

    // ---- layer 0 ----
    k_msg<<<2 * NBLK_E, 256, 0, stream>>>(h_ab, ha0, ei_ab, W2_ab, b2_ab, ssum_b,
                                          h_ba, hb0, ei_ba, W2_ba, b2_ba, ssum_a);
    k_node_update<<<2 * NBLK_N, 256, 0, stream>>>(
        ha0, root0_ba, bias0_ba, ssum_a, cnt_a, na1,
        hb0, root0_ab, bias0_ab, ssum_b, cnt_b, nb1, /*zero_ssum=*/1);

    // ---- layer 1 (writes d_out) ----
    k_msg<<<2 * NBLK_E, 256, 0, stream>>>(h_ab, na1, ei_ab, W2_ab, b2_ab, ssum_b,
                                          h_ba, nb1, ei_ba, W2_ba, b2_ba, ssum_a);
    k_node_update<<<2 * NBLK_N, 256, 0, stream>>>(
        na1, root1_ba, bias1_ba, ssum_a, cnt_a, out_a,
        nb1, root1_ab, bias1_ab, ssum_b, cnt_b, out_b, /*zero_ssum=*/0);
}

// Round 6
// 303.625 us; speedup vs baseline: 5.3258x; 5.3258x over previous
//
#include <hip/hip_runtime.h>

#define NA_N 50000
#define NB_N 50000
#define DIM  64
#define NE   30000
#define FE_N 16
#define NBLK_E 469          // ceil(30000/64)
#define NBLK_N 782          // ceil(50000/64)

typedef __attribute__((ext_vector_type(8))) short bf16x8;
typedef __attribute__((ext_vector_type(4))) float f32x4;

__device__ __forceinline__ unsigned short f2bf(float f) {
    union { float f; unsigned u; } v; v.f = f;
    return (unsigned short)((v.u + 0x7FFFu + ((v.u >> 16) & 1u)) >> 16);  // RNE
}

// ---------------------------------------------------------------------------
// Fused node init: out[n,:] = emb[idx[n],:] @ W + bias  (fp32 + bf16 copy)
// ---------------------------------------------------------------------------
__global__ __launch_bounds__(256) void k_node_init(
    const int* __restrict__ idx_a, const float* __restrict__ emb_a,
    const float* __restrict__ Wa, const float* __restrict__ ba_,
    float* __restrict__ out_a, unsigned short* __restrict__ xbf_a,
    const int* __restrict__ idx_b, const float* __restrict__ emb_b,
    const float* __restrict__ Wb, const float* __restrict__ bb_,
    float* __restrict__ out_b, unsigned short* __restrict__ xbf_b)
{
    __shared__ __align__(16) float XsT[64][68];
    __shared__ __align__(16) float Ws[64][64];

    const bool isA = blockIdx.x < NBLK_N;
    const int  blk = isA ? blockIdx.x : blockIdx.x - NBLK_N;
    const int*   idx  = isA ? idx_a : idx_b;
    const float* emb  = isA ? emb_a : emb_b;
    const float* W    = isA ? Wa : Wb;
    const float* bias = isA ? ba_ : bb_;
    float*       out  = isA ? out_a : out_b;
    unsigned short* xbf = isA ? xbf_a : xbf_b;
    const int    N    = isA ? NA_N : NB_N;

    const int t  = threadIdx.x;
    const int n0 = blk * 64;

    {
        const float4* Wv  = (const float4*)W;
        float4*       Wsv = (float4*)&Ws[0][0];
#pragma unroll
        for (int i = 0; i < 4; ++i) Wsv[t + 256 * i] = Wv[t + 256 * i];
    }
    {
        const int r = t >> 2, q = t & 3;
        const int n = n0 + r;
        if (n < N) {
            const int g = idx[n];
            const float4* src = (const float4*)(emb + (size_t)g * DIM);
#pragma unroll
            for (int i = 0; i < 4; ++i) {
                float4 v = src[q * 4 + i];
                XsT[q * 16 + i * 4 + 0][r] = v.x;
                XsT[q * 16 + i * 4 + 1][r] = v.y;
                XsT[q * 16 + i * 4 + 2][r] = v.z;
                XsT[q * 16 + i * 4 + 3][r] = v.w;
            }
        } else {
#pragma unroll
            for (int i = 0; i < 16; ++i) XsT[q * 16 + i][r] = 0.f;
        }
    }
    __syncthreads();

    const int tr = t >> 4, tc = t & 15;
    float acc[4][4] = {};
    for (int d = 0; d < 64; ++d) {
        const float4 xv = *(const float4*)&XsT[d][tr * 4];
        const float4 wv = *(const float4*)&Ws[d][tc * 4];
        acc[0][0] += xv.x * wv.x; acc[0][1] += xv.x * wv.y;
        acc[0][2] += xv.x * wv.z; acc[0][3] += xv.x * wv.w;
        acc[1][0] += xv.y * wv.x; acc[1][1] += xv.y * wv.y;
        acc[1][2] += xv.y * wv.z; acc[1][3] += xv.y * wv.w;
        acc[2][0] += xv.z * wv.x; acc[2][1] += xv.z * wv.y;
        acc[2][2] += xv.z * wv.z; acc[2][3] += xv.z * wv.w;
        acc[3][0] += xv.w * wv.x; acc[3][1] += xv.w * wv.y;
        acc[3][2] += xv.w * wv.z; acc[3][3] += xv.w * wv.w;
    }
    const float4 bv = *(const float4*)(bias + tc * 4);
#pragma unroll
    for (int i = 0; i < 4; ++i) {
        const int n = n0 + tr * 4 + i;
        if (n < N) {
            float4 o;
            o.x = acc[i][0] + bv.x;
            o.y = acc[i][1] + bv.y;
            o.z = acc[i][2] + bv.z;
            o.w = acc[i][3] + bv.w;
            *(float4*)(out + (size_t)n * DIM + tc * 4) = o;
            ushort4 ob;
            ob.x = f2bf(o.x); ob.y = f2bf(o.y); ob.z = f2bf(o.z); ob.w = f2bf(o.w);
            *(ushort4*)(xbf + (size_t)n * DIM + tc * 4) = ob;
        }
    }
}

// ---------------------------------------------------------------------------
// Fused node update (in-place safe: x/out may alias — no restrict on them):
// out = relu( ssum/max(cnt,1) + x @ root + bias ); bf16 copy; opt. re-zero ssum.
// ---------------------------------------------------------------------------
__global__ __launch_bounds__(256) void k_node_update(
    const float* xa, const float* __restrict__ roota,
    const float* __restrict__ biasa, float* __restrict__ ssa,
    const float* __restrict__ cnta, float* outa, unsigned short* __restrict__ xbfa,
    const float* xb, const float* __restrict__ rootb,
    const float* __restrict__ biasb, float* __restrict__ ssb,
    const float* __restrict__ cntb, float* outb, unsigned short* __restrict__ xbfb,
    int zero_ssum)
{
    __shared__ __align__(16) float XsT[64][68];
    __shared__ __align__(16) float Ws[64][64];

    const bool isA = blockIdx.x < NBLK_N;
    const int  blk = isA ? blockIdx.x : blockIdx.x - NBLK_N;
    const float* x    = isA ? xa : xb;
    const float* root = isA ? roota : rootb;
    const float* bias = isA ? biasa : biasb;
    float*       ssum = isA ? ssa : ssb;
    const float* cnt  = isA ? cnta : cntb;
    float*       out  = isA ? outa : outb;
    unsigned short* xbf = isA ? xbfa : xbfb;
    const int    N    = isA ? NA_N : NB_N;

    const int t  = threadIdx.x;
    const int n0 = blk * 64;

    {
        const float4* Wv  = (const float4*)root;
        float4*       Wsv = (float4*)&Ws[0][0];
#pragma unroll
        for (int i = 0; i < 4; ++i) Wsv[t + 256 * i] = Wv[t + 256 * i];
    }
    {
        const int r = t >> 2, q = t & 3;
        const int n = n0 + r;
        if (n < N) {
            const float4* src = (const float4*)(x + (size_t)n * DIM);
#pragma unroll
            for (int i = 0; i < 4; ++i) {
                float4 v = src[q * 4 + i];
                XsT[q * 16 + i * 4 + 0][r] = v.x;
                XsT[q * 16 + i * 4 + 1][r] = v.y;
                XsT[q * 16 + i * 4 + 2][r] = v.z;
                XsT[q * 16 + i * 4 + 3][r] = v.w;
            }
        } else {
#pragma unroll
            for (int i = 0; i < 16; ++i) XsT[q * 16 + i][r] = 0.f;
        }
    }
    __syncthreads();

    const int tr = t >> 4, tc = t & 15;
    float acc[4][4] = {};
    for (int d = 0; d < 64; ++d) {
        const float4 xv = *(const float4*)&XsT[d][tr * 4];
        const float4 wv = *(const float4*)&Ws[d][tc * 4];
        acc[0][0] += xv.x * wv.x; acc[0][1] += xv.x * wv.y;
        acc[0][2] += xv.x * wv.z; acc[0][3] += xv.x * wv.w;
        acc[1][0] += xv.y * wv.x; acc[1][1] += xv.y * wv.y;
        acc[1][2] += xv.y * wv.z; acc[1][3] += xv.y * wv.w;
        acc[2][0] += xv.z * wv.x; acc[2][1] += xv.z * wv.y;
        acc[2][2] += xv.z * wv.z; acc[2][3] += xv.z * wv.w;
        acc[3][0] += xv.w * wv.x; acc[3][1] += xv.w * wv.y;
        acc[3][2] += xv.w * wv.z; acc[3][3] += xv.w * wv.w;
    }
    const float4 bv = *(const float4*)(bias + tc * 4);
#pragma unroll
    for (int i = 0; i < 4; ++i) {
        const int n = n0 + tr * 4 + i;
        if (n < N) {
            const float inv = 1.0f / fmaxf(cnt[n], 1.0f);
            float* sp = ssum + (size_t)n * DIM + tc * 4;
            const float4 s = *(const float4*)sp;
            float4 o;
            o.x = fmaxf(acc[i][0] + s.x * inv + bv.x, 0.f);
            o.y = fmaxf(acc[i][1] + s.y * inv + bv.y, 0.f);
            o.z = fmaxf(acc[i][2] + s.z * inv + bv.z, 0.f);
            o.w = fmaxf(acc[i][3] + s.w * inv + bv.w, 0.f);
            *(float4*)(out + (size_t)n * DIM + tc * 4) = o;
            ushort4 ob;
            ob.x = f2bf(o.x); ob.y = f2bf(o.y); ob.z = f2bf(o.z); ob.w = f2bf(o.w);
            *(ushort4*)(xbf + (size_t)n * DIM + tc * 4) = ob;
            if (zero_ssum) *(float4*)sp = make_float4(0.f, 0.f, 0.f, 0.f);
        }
    }
}

// ---------------------------------------------------------------------------
// Fused edge MLP: h[e,:] = relu( ea[e,:] @ W1 + b1 ), both edge types (fp32).
// ---------------------------------------------------------------------------
__global__ __launch_bounds__(256) void k_edge_h(
    const float* __restrict__ ea_ab, const float* __restrict__ W1_ab,
    const float* __restrict__ b1_ab, float* __restrict__ h_ab,
    const float* __restrict__ ea_ba, const float* __restrict__ W1_ba,
    const float* __restrict__ b1_ba, float* __restrict__ h_ba)
{
    __shared__ __align__(16) float As[64][17];
    __shared__ __align__(16) float Ws[16][64];

    const bool isAB = blockIdx.x < NBLK_E;
    const int  blk  = isAB ? blockIdx.x : blockIdx.x - NBLK_E;
    const float* ea = isAB ? ea_ab : ea_ba;
    const float* W1 = isAB ? W1_ab : W1_ba;
    const float* b1 = isAB ? b1_ab : b1_ba;
    float*       h  = isAB ? h_ab : h_ba;

    const int t  = threadIdx.x;
    const int e0 = blk * 64;

    ((float4*)&Ws[0][0])[t] = ((const float4*)W1)[t];
    {
        const int r = t >> 2, q = t & 3;
        const int e = e0 + r;
        float4 v = make_float4(0.f, 0.f, 0.f, 0.f);
        if (e < NE) v = ((const float4*)(ea + (size_t)e * FE_N))[q];
        As[r][q * 4 + 0] = v.x;
        As[r][q * 4 + 1] = v.y;
        As[r][q * 4 + 2] = v.z;
        As[r][q * 4 + 3] = v.w;
    }
    __syncthreads();

    const int tr = t >> 4, tc = t & 15;
    float acc[4][4] = {};
    for (int d = 0; d < 16; ++d) {
        float xv[4];
#pragma unroll
        for (int i = 0; i < 4; ++i) xv[i] = As[tr * 4 + i][d];
        const float4 wv = *(const float4*)&Ws[d][tc * 4];
#pragma unroll
        for (int i = 0; i < 4; ++i) {
            acc[i][0] += xv[i] * wv.x;
            acc[i][1] += xv[i] * wv.y;
            acc[i][2] += xv[i] * wv.z;
            acc[i][3] += xv[i] * wv.w;
        }
    }
    const float4 bv = *(const float4*)(b1 + tc * 4);
#pragma unroll
    for (int i = 0; i < 4; ++i) {
        const int e = e0 + tr * 4 + i;
        if (e < NE) {
            float4 o;
            o.x = fmaxf(acc[i][0] + bv.x, 0.f);
            o.y = fmaxf(acc[i][1] + bv.y, 0.f);
            o.z = fmaxf(acc[i][2] + bv.z, 0.f);
            o.w = fmaxf(acc[i][3] + bv.w, 0.f);
            *(float4*)(h + (size_t)e * DIM + tc * 4) = o;
        }
    }
}

// ---------------------------------------------------------------------------
__global__ void k_count(const int* __restrict__ dst_ab, const int* __restrict__ dst_ba,
                        float* __restrict__ cnt_b, float* __restrict__ cnt_a)
{
    const int i = blockIdx.x * blockDim.x + threadIdx.x;
    if (i < NE)            atomicAdd(&cnt_b[dst_ab[i]], 1.0f);
    else if (i < 2 * NE)   atomicAdd(&cnt_a[dst_ba[i - NE]], 1.0f);
}

// ---------------------------------------------------------------------------
// Pack W2 (+b2 as k-slot 64) into bf16 MFMA-fragment layout:
//   Wp[(k*2+c)*2048 + o*32 + dd] = bf16( k<64 ? W2[k*4096+(c*32+dd)*64+o]
//                                             : b2[(c*32+dd)*64+o] )
// ---------------------------------------------------------------------------
__global__ void k_pack(const float* __restrict__ W2a, const float* __restrict__ b2a,
                       unsigned short* __restrict__ Pa,
                       const float* __restrict__ W2b, const float* __restrict__ b2b,
                       unsigned short* __restrict__ Pb)
{
    const int idx = blockIdx.x * 256 + threadIdx.x;   // 2 * 65 * 4096 total
    const int per = 65 * 4096;
    if (idx >= 2 * per) return;
    const int typ = idx / per;
    const int p   = idx - typ * per;
    const int k   = p >> 12;
    const int c   = (p >> 11) & 1;
    const int q   = p & 2047;
    const int o   = q >> 5;
    const int dd  = q & 31;
    const int d   = c * 32 + dd;
    const float* W2 = typ ? W2b : W2a;
    const float* b2 = typ ? b2b : b2a;
    const float  f  = (k < 64) ? W2[k * 4096 + d * 64 + o] : b2[d * 64 + o];
    (typ ? Pb : Pa)[p] = f2bf(f);
}

// ---------------------------------------------------------------------------
// MFMA message+scatter, both edge types. Per block: 64 edges.
// Wave w owns o-columns [16w,16w+16). A (x tile) in regs (k-invariant);
// B fragments stream from packed W2p via coalesced 16B global loads,
// register-prefetched one k ahead; h^T staged once in LDS. No k-loop barriers.
//   G_k = X @ B_k  (2 chained MFMAs / 16x16 tile, C=0)
//   acc += h[:,k] * G_k   (fp32 fold)
// ---------------------------------------------------------------------------
__global__ __launch_bounds__(256) void k_msg(
    const float* __restrict__ h_ab, const unsigned short* __restrict__ x_ab,
    const int* __restrict__ ei_ab, const unsigned short* __restrict__ Wp_ab,
    float* __restrict__ ssum_b,
    const float* __restrict__ h_ba, const unsigned short* __restrict__ x_ba,
    const int* __restrict__ ei_ba, const unsigned short* __restrict__ Wp_ba,
    float* __restrict__ ssum_a)
{
    __shared__ __align__(16) float HsT[65][68];   // [k][e_local]

    const bool isAB = blockIdx.x < NBLK_E;
    const int  blk  = isAB ? blockIdx.x : blockIdx.x - NBLK_E;
    const float*          h    = isAB ? h_ab : h_ba;
    const unsigned short* x    = isAB ? x_ab : x_ba;
    const int*            srcI = isAB ? ei_ab : ei_ba;
    const int*            dstI = srcI + NE;
    const unsigned short* Wp   = isAB ? Wp_ab : Wp_ba;
    float*                ssum = isAB ? ssum_b : ssum_a;

    const int t  = threadIdx.x;
    const int e0 = blk * 64;
    const int l  = t & 63;
    const int wv = t >> 6;      // wave = o-column tile
    const int lo = l & 15;
    const int hi = l >> 4;

    // ---- stage h^T (HsT[k][e]); slot 64 = 1.0 for the b2 term ----
    {
        const int el = t >> 2, q = t & 3;
        const float4* hp = (const float4*)(h + (size_t)(e0 + el) * DIM + q * 16);
#pragma unroll
        for (int i = 0; i < 4; ++i) {
            const float4 v = hp[i];     // tail-block reads land in ws (safe, discarded)
            HsT[q * 16 + i * 4 + 0][el] = v.x;
            HsT[q * 16 + i * 4 + 1][el] = v.y;
            HsT[q * 16 + i * 4 + 2][el] = v.z;
            HsT[q * 16 + i * 4 + 3][el] = v.w;
        }
        if (t < 64) HsT[64][t] = 1.0f;
    }

    // ---- k-invariant A fragments: row = e0+rt*16+lo, d = c*32 + hi*8 + j ----
    bf16x8 A[4][2];
#pragma unroll
    for (int rt = 0; rt < 4; ++rt) {
        const int s = srcI[e0 + rt * 16 + lo];        // in-bounds even for tail
        const unsigned short* xp = x + (size_t)s * DIM + hi * 8;
        A[rt][0] = *(const bf16x8*)(xp);
        A[rt][1] = *(const bf16x8*)(xp + 32);
    }

    // ---- B fragment stream: lane-fixed offset inside each (k,c) 2048-elem slice
    const unsigned short* Wl = Wp + wv * 512 + lo * 32 + hi * 8;
    bf16x8 B0 = *(const bf16x8*)(Wl);
    bf16x8 B1 = *(const bf16x8*)(Wl + 2048);

    __syncthreads();

    f32x4 acc[4] = {};
    const f32x4 zf = {0.f, 0.f, 0.f, 0.f};

    for (int k = 0; k < 65; ++k) {
        bf16x8 N0, N1;
        if (k < 64) {                                  // prefetch k+1
            const unsigned short* nw = Wl + (size_t)(k + 1) * 4096;
            N0 = *(const bf16x8*)(nw);
            N1 = *(const bf16x8*)(nw + 2048);
        }
#pragma unroll
        for (int rt = 0; rt < 4; ++rt) {
            f32x4 g = __builtin_amdgcn_mfma_f32_16x16x32_bf16(A[rt][0], B0, zf, 0, 0, 0);
            g = __builtin_amdgcn_mfma_f32_16x16x32_bf16(A[rt][1], B1, g, 0, 0, 0);
            const f32x4 hv = *(const f32x4*)&HsT[k][rt * 16 + hi * 4];
            acc[rt] += hv * g;
        }
        if (k < 64) { B0 = N0; B1 = N1; }
    }

    // ---- scatter: C layout col = lo (o), row = hi*4 + i ----
    const int oo = (wv << 4) + lo;
#pragma unroll
    for (int rt = 0; rt < 4; ++rt) {
        const int eb = e0 + rt * 16 + (hi << 2);
        if (eb + 3 < NE) {
            const int4 dn = *(const int4*)(dstI + eb);
            atomicAdd(ssum + (size_t)dn.x * DIM + oo, acc[rt].x);
            atomicAdd(ssum + (size_t)dn.y * DIM + oo, acc[rt].y);
            atomicAdd(ssum + (size_t)dn.z * DIM + oo, acc[rt].z);
            atomicAdd(ssum + (size_t)dn.w * DIM + oo, acc[rt].w);
        } else {
#pragma unroll
            for (int i = 0; i < 4; ++i)
                if (eb + i < NE)
                    atomicAdd(ssum + (size_t)dstI[eb + i] * DIM + oo, acc[rt][i]);
        }
    }
}

// ---------------------------------------------------------------------------
extern "C" void kernel_launch(void* const* d_in, const int* in_sizes, int n_in,
                              void* d_out, int out_size, void* d_ws, size_t ws_size,
                              hipStream_t stream)
{
    (void)in_sizes; (void)n_in; (void)out_size; (void)ws_size;

    const int*   x_a      = (const int*)d_in[0];
    const int*   x_b      = (const int*)d_in[1];
    const int*   ei_ab    = (const int*)d_in[2];   // [2][E]: row0 src(a), row1 dst(b)
    const int*   ei_ba    = (const int*)d_in[3];   // row0 src(b), row1 dst(a)
    const float* ea_ab    = (const float*)d_in[4];
    const float* ea_ba    = (const float*)d_in[5];
    const float* emb_a    = (const float*)d_in[6];
    const float* emb_b    = (const float*)d_in[7];
    const float* Wn_a     = (const float*)d_in[8];
    const float* bn_a     = (const float*)d_in[9];
    const float* Wn_b     = (const float*)d_in[10];
    const float* bn_b     = (const float*)d_in[11];
    const float* W1_ab    = (const float*)d_in[12];
    const float* b1_ab    = (const float*)d_in[13];
    const float* W2_ab    = (const float*)d_in[14];
    const float* b2_ab    = (const float*)d_in[15];
    const float* W1_ba    = (const float*)d_in[16];
    const float* b1_ba    = (const float*)d_in[17];
    const float* W2_ba    = (const float*)d_in[18];
    const float* b2_ba    = (const float*)d_in[19];
    const float* root0_ab = (const float*)d_in[20];
    const float* bias0_ab = (const float*)d_in[21];
    const float* root0_ba = (const float*)d_in[22];
    const float* bias0_ba = (const float*)d_in[23];
    const float* root1_ab = (const float*)d_in[24];
    const float* bias1_ab = (const float*)d_in[25];
    const float* root1_ba = (const float*)d_in[26];
    const float* bias1_ba = (const float*)d_in[27];

    float* out_a = (float*)d_out;
    float* out_b = (float*)d_out + (size_t)NA_N * DIM;

    // workspace layout (float units; every base 64B-aligned)
    float* ws     = (float*)d_ws;
    float* ha0    = ws;                            // NA*64 (layer-1 a-features in place)
    float* hb0    = ha0    + (size_t)NA_N * DIM;   // NB*64
    float* h_ab   = hb0    + (size_t)NB_N * DIM;   // E*64
    float* h_ba   = h_ab   + (size_t)NE * DIM;     // E*64
    float* cnt_a  = h_ba   + (size_t)NE * DIM;     // NA   } contiguous
    float* cnt_b  = cnt_a  + NA_N;                 // NB   } memset
    float* ssum_a = cnt_b  + NB_N;                 // NA*64}
    float* ssum_b = ssum_a + (size_t)NA_N * DIM;   // NB*64}
    unsigned short* xbf_a = (unsigned short*)(ssum_b + (size_t)NB_N * DIM); // NA*64 u16
    unsigned short* xbf_b = xbf_a + (size_t)NA_N * DIM;                     // NB*64 u16
    unsigned short* Wp_ab = xbf_b + (size_t)NB_N * DIM;                     // 65*4096 u16
    unsigned short* Wp_ba = Wp_ab + 65 * 4096;                              // 65*4096 u16

    const size_t zeroBytes =
        ((size_t)(NA_N + NB_N) + (size_t)(NA_N + NB_N) * DIM) * sizeof(float);
    hipMemsetAsync(cnt_a, 0, zeroBytes, stream);

    k_count<<<(2 * NE + 255) / 256, 256, 0, stream>>>(ei_ab + NE, ei_ba + NE,
                                                      cnt_b, cnt_a);
    k_node_init<<<2 * NBLK_N, 256, 0, stream>>>(x_a, emb_a, Wn_a, bn_a, ha0, xbf_a,
                                                x_b, emb_b, Wn_b, bn_b, hb0, xbf_b);
    k_edge_h<<<2 * NBLK_E, 256, 0, stream>>>(ea_ab, W1_ab, b1_ab, h_ab,
                                             ea_ba, W1_ba, b1_ba, h_ba);
    k_pack<<<(2 * 65 * 4096 + 255) / 256, 256, 0, stream>>>(W2_ab, b2_ab, Wp_ab,
                                                            W2_ba, b2_ba, Wp_ba);

    // ---- layer 0 ----
    k_msg<<<2 * NBLK_E, 256, 0, stream>>>(h_ab, xbf_a, ei_ab, Wp_ab, ssum_b,
                                          h_ba, xbf_b, ei_ba, Wp_ba, ssum_a);
    k_node_update<<<2 * NBLK_N, 256, 0, stream>>>(
        ha0, root0_ba, bias0_ba, ssum_a, cnt_a, ha0, xbf_a,   // in-place a
        hb0, root0_ab, bias0_ab, ssum_b, cnt_b, hb0, xbf_b,   // in-place b
        /*zero_ssum=*/1);

    // ---- layer 1 (writes d_out) ----
    k_msg<<<2 * NBLK_E, 256, 0, stream>>>(h_ab, xbf_a, ei_ab, Wp_ab, ssum_b,
                                          h_ba, xbf_b, ei_ba, Wp_ba, ssum_a);
    k_node_update<<<2 * NBLK_N, 256, 0, stream>>>(
        ha0, root1_ba, bias1_ba, ssum_a, cnt_a, out_a, xbf_a,
        hb0, root1_ab, bias1_ab, ssum_b, cnt_b, out_b, xbf_b,
        /*zero_ssum=*/0);
}